// Round 2
// baseline (502.642 us; speedup 1.0000x reference)
//
#include <hip/hip_runtime.h>
#include <math.h>

// ContextualNeuronPool: B=2,S=2048,K=8,POOL=512,DM=1024,DFF=4096,MD=64
// All float inputs/outputs are FLOAT32 (per reference dtypes). Internally we
// convert GEMM operands to bf16 for MFMA (rel err ~2^-9 << 2% threshold).
#define T_    4096   // B*S tokens
#define K_    8
#define POOL_ 512
#define DM_   1024
#define DFF_  4096
#define MD_   64

typedef __bf16 bf16x8 __attribute__((ext_vector_type(8)));
typedef __bf16 bf16x4 __attribute__((ext_vector_type(4)));
typedef float  f32x4  __attribute__((ext_vector_type(4)));

typedef __attribute__((address_space(1))) const void g_void;
typedef __attribute__((address_space(3))) void s_void;

__device__ __forceinline__ void async_ld16(const void* g, void* s) {
    // global -> LDS direct DMA, 16B/lane (dest = wave-uniform base + lane*16)
    __builtin_amdgcn_global_load_lds((g_void*)g, (s_void*)s, 16, 0, 0);
}

__device__ __forceinline__ float gelu_exact(float g) {
    return 0.5f * g * (1.f + erff(g * 0.70710678118654752f));
}

// ---------------------------------------------------------------------------
// K0: wholesale f32 -> bf16 convert (used for w2). n16 = n/16.
// ---------------------------------------------------------------------------
__global__ __launch_bounds__(256) void k_cvt(const float* __restrict__ src,
                                             __bf16* __restrict__ dst, int n16) {
    int i = blockIdx.x * 256 + threadIdx.x;
    if (i >= n16) return;
    const float4* s = (const float4*)src + (long)i * 4;
    float4 a = s[0], b = s[1], c = s[2], d = s[3];
    bf16x8 o0, o1;
    o0[0]=(__bf16)a.x; o0[1]=(__bf16)a.y; o0[2]=(__bf16)a.z; o0[3]=(__bf16)a.w;
    o0[4]=(__bf16)b.x; o0[5]=(__bf16)b.y; o0[6]=(__bf16)b.z; o0[7]=(__bf16)b.w;
    o1[0]=(__bf16)c.x; o1[1]=(__bf16)c.y; o1[2]=(__bf16)c.z; o1[3]=(__bf16)c.w;
    o1[4]=(__bf16)d.x; o1[5]=(__bf16)d.y; o1[6]=(__bf16)d.z; o1[7]=(__bf16)d.w;
    bf16x8* dp = (bf16x8*)dst + (long)i * 2;
    dp[0] = o0; dp[1] = o1;
}

// ---------------------------------------------------------------------------
// K1: expert-grouped sel_mod. Block p: collect pairs with sel==p, then MFMA
//     Y[pair][m] = dot(x[token], cm_w[p*64+m]) + cm_b[p*64+m]   (f32 out)
//     x, cm_w are f32 in HBM; converted to bf16 while staging to LDS.
// ---------------------------------------------------------------------------
__global__ __launch_bounds__(256) void k_selmod(
    const float* __restrict__ x, const int* __restrict__ sel,
    const float* __restrict__ cm_w, const float* __restrict__ cm_b,
    float* __restrict__ Y)
{
    const int p   = blockIdx.x;
    const int tid = threadIdx.x;
    __shared__ int cnt;
    __shared__ int list[1024];
    __shared__ __align__(16) __bf16 Xl[64][136];  // +8 pad
    __shared__ __align__(16) __bf16 Wl[64][136];

    if (tid == 0) cnt = 0;
    __syncthreads();
    for (int i = tid; i < T_ * K_; i += 256) {
        if (sel[i] == p) { int pos = atomicAdd(&cnt, 1); if (pos < 1024) list[pos] = i; }
    }
    __syncthreads();
    const int n = min(cnt, 1024);
    if (n == 0) return;

    const int wave = tid >> 6, lane = tid & 63, quad = lane >> 4, l15 = lane & 15;
    const int srow = tid & 63;           // staging row this thread fills
    const int c0   = (tid >> 6) * 32;    // staging col base (32 elements)

    const float* wrow = cm_w + (long)(p * 64 + srow) * DM_;

    for (int base = 0; base < n; base += 64) {
        f32x4 acc[4] = {};
        int li = base + srow; if (li >= n) li = n - 1;   // clamp: dup row, masked write
        const float* xrow = x + (long)(list[li] >> 3) * DM_;

        for (int kc = 0; kc < DM_; kc += 128) {
            const float4* xs = (const float4*)(xrow + kc + c0);
            const float4* ws = (const float4*)(wrow + kc + c0);
            #pragma unroll
            for (int u = 0; u < 8; ++u) {
                float4 xv = xs[u], wv = ws[u];
                bf16x4 xb, wb;
                xb[0]=(__bf16)xv.x; xb[1]=(__bf16)xv.y; xb[2]=(__bf16)xv.z; xb[3]=(__bf16)xv.w;
                wb[0]=(__bf16)wv.x; wb[1]=(__bf16)wv.y; wb[2]=(__bf16)wv.z; wb[3]=(__bf16)wv.w;
                *(bf16x4*)&Xl[srow][c0 + u * 4] = xb;
                *(bf16x4*)&Wl[srow][c0 + u * 4] = wb;
            }
            __syncthreads();
            #pragma unroll
            for (int ks = 0; ks < 4; ++ks) {
                const int ko = ks * 32 + quad * 8;
                bf16x8 bfr = *(const bf16x8*)&Wl[wave * 16 + l15][ko];
                #pragma unroll
                for (int i = 0; i < 4; ++i) {
                    bf16x8 afr = *(const bf16x8*)&Xl[i * 16 + l15][ko];
                    acc[i] = __builtin_amdgcn_mfma_f32_16x16x32_bf16(afr, bfr, acc[i], 0, 0, 0);
                }
            }
            __syncthreads();
        }
        const int   mcol = wave * 16 + l15;
        const float bias = cm_b[p * 64 + mcol];
        #pragma unroll
        for (int i = 0; i < 4; ++i) {
            #pragma unroll
            for (int r = 0; r < 4; ++r) {
                int prow = base + i * 16 + quad * 4 + r;   // C/D: row=quad*4+reg, col=lane&15
                if (prow < n)
                    Y[(long)list[prow] * MD_ + mcol] = acc[i][r] + bias;
            }
        }
    }
}

// ---------------------------------------------------------------------------
// K2: 8 tokens per block. softmax(pw), wmod = sum_k w_k*Y[t,k,:],
//     act[t][f] = gelu( sum_k w_k*bp[idx_k][f] + sum_m wmod[m]*adj[m][f] )
//     bp/adj/pw/Y f32; act written bf16.
// ---------------------------------------------------------------------------
__global__ __launch_bounds__(256) void k_combine(
    const float* __restrict__ Y, const int* __restrict__ sel,
    const float* __restrict__ pw, const float* __restrict__ bp,
    const float* __restrict__ adj, __bf16* __restrict__ act)
{
    const int t0 = blockIdx.x * 8, tid = threadIdx.x;
    __shared__ float w_s[8][8];
    __shared__ float wm_s[8][64];
    __shared__ int   sel_s[64];

    if (tid < 64) {
        w_s[tid >> 3][tid & 7] = pw[t0 * 8 + tid];
        sel_s[tid] = sel[t0 * 8 + tid];
    }
    __syncthreads();
    if (tid < 8) {
        float mx = w_s[tid][0];
        #pragma unroll
        for (int k = 1; k < 8; ++k) mx = fmaxf(mx, w_s[tid][k]);
        float sum = 0.f;
        #pragma unroll
        for (int k = 0; k < 8; ++k) { float e = expf(w_s[tid][k] - mx); w_s[tid][k] = e; sum += e; }
        float inv = 1.f / sum;
        #pragma unroll
        for (int k = 0; k < 8; ++k) w_s[tid][k] *= inv;
    }
    __syncthreads();
    for (int idx = tid; idx < 512; idx += 256) {
        int tt = idx >> 6, m = idx & 63;
        float a = 0.f;
        #pragma unroll
        for (int k = 0; k < 8; ++k)
            a += w_s[tt][k] * Y[((long)(t0 + tt) * K_ + k) * MD_ + m];
        wm_s[tt][m] = a;
    }
    __syncthreads();

    const int f0 = tid * 16;
    float acc[8][16];
    #pragma unroll
    for (int tt = 0; tt < 8; ++tt)
        #pragma unroll
        for (int j = 0; j < 16; ++j) acc[tt][j] = 0.f;

    // base-pattern gather: 64 rows, 16 cols each
    #pragma unroll
    for (int tt = 0; tt < 8; ++tt) {
        #pragma unroll
        for (int k = 0; k < 8; ++k) {
            const float wk = w_s[tt][k];
            const float4* r = (const float4*)(bp + (long)sel_s[tt * 8 + k] * DFF_ + f0);
            float4 v0 = r[0], v1 = r[1], v2 = r[2], v3 = r[3];
            acc[tt][0]  += wk * v0.x; acc[tt][1]  += wk * v0.y; acc[tt][2]  += wk * v0.z; acc[tt][3]  += wk * v0.w;
            acc[tt][4]  += wk * v1.x; acc[tt][5]  += wk * v1.y; acc[tt][6]  += wk * v1.z; acc[tt][7]  += wk * v1.w;
            acc[tt][8]  += wk * v2.x; acc[tt][9]  += wk * v2.y; acc[tt][10] += wk * v2.z; acc[tt][11] += wk * v2.w;
            acc[tt][12] += wk * v3.x; acc[tt][13] += wk * v3.y; acc[tt][14] += wk * v3.z; acc[tt][15] += wk * v3.w;
        }
    }
    // adjustment matvec: adj rows shared across the 8 tokens
    #pragma unroll 2
    for (int m = 0; m < 64; ++m) {
        const float4* r = (const float4*)(adj + (long)m * DFF_ + f0);
        float4 v0 = r[0], v1 = r[1], v2 = r[2], v3 = r[3];
        #pragma unroll
        for (int tt = 0; tt < 8; ++tt) {
            const float wm = wm_s[tt][m];
            acc[tt][0]  += wm * v0.x; acc[tt][1]  += wm * v0.y; acc[tt][2]  += wm * v0.z; acc[tt][3]  += wm * v0.w;
            acc[tt][4]  += wm * v1.x; acc[tt][5]  += wm * v1.y; acc[tt][6]  += wm * v1.z; acc[tt][7]  += wm * v1.w;
            acc[tt][8]  += wm * v2.x; acc[tt][9]  += wm * v2.y; acc[tt][10] += wm * v2.z; acc[tt][11] += wm * v2.w;
            acc[tt][12] += wm * v3.x; acc[tt][13] += wm * v3.y; acc[tt][14] += wm * v3.z; acc[tt][15] += wm * v3.w;
        }
    }

    #pragma unroll
    for (int tt = 0; tt < 8; ++tt) {
        bf16x8 o0, o1;
        #pragma unroll
        for (int j = 0; j < 8; ++j) {
            o0[j] = (__bf16)gelu_exact(acc[tt][j]);
            o1[j] = (__bf16)gelu_exact(acc[tt][8 + j]);
        }
        bf16x8* dst = (bf16x8*)(act + (long)(t0 + tt) * DFF_ + f0);
        dst[0] = o0; dst[1] = o1;
    }
}

// ---------------------------------------------------------------------------
// K3: out[4096x1024] = act[4096x4096](bf16) @ w2bf[1024x4096]^T + w2_b(f32)
//     128x128 tile, BK=32, global_load_lds width-16 staging (m97 structure)
// ---------------------------------------------------------------------------
__global__ __launch_bounds__(256) void k_outgemm(
    const __bf16* __restrict__ A, const __bf16* __restrict__ Bw,
    const float* __restrict__ bias, float* __restrict__ out)
{
    __shared__ __align__(16) __bf16 sA[128 * 32];
    __shared__ __align__(16) __bf16 sB[128 * 32];
    const int tid  = threadIdx.x;
    const int tm   = blockIdx.y * 128, tn = blockIdx.x * 128;
    const int wave = tid >> 6, lane = tid & 63, quad = lane >> 4, l15 = lane & 15;
    const int wm   = (wave >> 1) * 64, wn = (wave & 1) * 64;

    f32x4 acc[4][4] = {};

    const int e    = tid * 8;         // bf16 elements; byte offset = tid*16
    const int srow = e >> 5;          // 0..63
    const int scol = e & 31;
    const __bf16* agp0 = A  + ((long)(tm + srow)      * DFF_ + scol);
    const __bf16* agp1 = A  + ((long)(tm + 64 + srow) * DFF_ + scol);
    const __bf16* bgp0 = Bw + ((long)(tn + srow)      * DFF_ + scol);
    const __bf16* bgp1 = Bw + ((long)(tn + 64 + srow) * DFF_ + scol);
    void* sa0 = (void*)(sA + e);
    void* sa1 = (void*)(sA + 2048 + e);
    void* sb0 = (void*)(sB + e);
    void* sb1 = (void*)(sB + 2048 + e);

    for (int kk = 0; kk < DFF_; kk += 32) {
        async_ld16(agp0 + kk, sa0);
        async_ld16(agp1 + kk, sa1);
        async_ld16(bgp0 + kk, sb0);
        async_ld16(bgp1 + kk, sb1);
        __syncthreads();
        bf16x8 af[4], bf[4];
        #pragma unroll
        for (int i = 0; i < 4; ++i)
            af[i] = *(const bf16x8*)(sA + (wm + i * 16 + l15) * 32 + quad * 8);
        #pragma unroll
        for (int j = 0; j < 4; ++j)
            bf[j] = *(const bf16x8*)(sB + (wn + j * 16 + l15) * 32 + quad * 8);
        #pragma unroll
        for (int i = 0; i < 4; ++i)
            #pragma unroll
            for (int j = 0; j < 4; ++j)
                acc[i][j] = __builtin_amdgcn_mfma_f32_16x16x32_bf16(af[i], bf[j], acc[i][j], 0, 0, 0);
        __syncthreads();
    }

    #pragma unroll
    for (int j = 0; j < 4; ++j) {
        const int col = tn + wn + j * 16 + l15;
        const float bj = bias[col];
        #pragma unroll
        for (int i = 0; i < 4; ++i) {
            const int row = tm + wm + i * 16 + quad * 4;
            #pragma unroll
            for (int r = 0; r < 4; ++r)
                out[(long)(row + r) * 1024 + col] = acc[i][j][r] + bj;
        }
    }
}

// ---------------------------------------------------------------------------
extern "C" void kernel_launch(void* const* d_in, const int* in_sizes, int n_in,
                              void* d_out, int out_size, void* d_ws, size_t ws_size,
                              hipStream_t stream) {
    const float* x    = (const float*)d_in[0];
    const int*   sel  = (const int*)  d_in[1];
    const float* pw   = (const float*)d_in[2];
    const float* bp   = (const float*)d_in[3];
    const float* cm_w = (const float*)d_in[4];
    const float* cm_b = (const float*)d_in[5];
    const float* adj  = (const float*)d_in[6];
    const float* w2   = (const float*)d_in[7];
    const float* w2b  = (const float*)d_in[8];
    float* out = (float*)d_out;

    // ws layout: Y f32 8MB | act bf16 32MB | w2bf bf16 8MB   (total 48MB)
    float*  Y    = (float*)d_ws;
    __bf16* act  = (__bf16*)((char*)d_ws + (size_t)8 * 1024 * 1024);
    __bf16* w2bf = (__bf16*)((char*)d_ws + (size_t)40 * 1024 * 1024);

    k_cvt    <<<(DM_ * DFF_ / 16 + 255) / 256, 256, 0, stream>>>(w2, w2bf, DM_ * DFF_ / 16);
    k_selmod <<<POOL_, 256, 0, stream>>>(x, sel, cm_w, cm_b, Y);
    k_combine<<<T_ / 8, 256, 0, stream>>>(Y, sel, pw, bp, adj, act);
    k_outgemm<<<dim3(DM_ / 128, T_ / 128), 256, 0, stream>>>(act, w2bf, w2b, out);
}

// Round 3
// 432.235 us; speedup vs baseline: 1.1629x; 1.1629x over previous
//
#include <hip/hip_runtime.h>
#include <math.h>

// ContextualNeuronPool: B=2,S=2048,K=8,POOL=512,DM=1024,DFF=4096,MD=64
// f32 inputs/outputs; internal GEMMs in bf16 MFMA.
#define T_    4096   // B*S tokens
#define K_    8
#define POOL_ 512
#define DM_   1024
#define DFF_  4096
#define MD_   64
#define KC_   576    // 512 (pool) + 64 (mod) combined contraction dim

typedef __bf16 bf16x8 __attribute__((ext_vector_type(8)));
typedef __bf16 bf16x4 __attribute__((ext_vector_type(4)));
typedef float  f32x4  __attribute__((ext_vector_type(4)));

typedef __attribute__((address_space(1))) const void g_void;
typedef __attribute__((address_space(3))) void s_void;

__device__ __forceinline__ void async_ld16(const void* g, void* s) {
    __builtin_amdgcn_global_load_lds((g_void*)g, (s_void*)s, 16, 0, 0);
}
__device__ __forceinline__ float gelu_exact(float g) {
    return 0.5f * g * (1.f + erff(g * 0.70710678118654752f));
}

// ---------------------------------------------------------------------------
// Binning: counting sort of the 32768 (token,k) pairs by pool index.
// ---------------------------------------------------------------------------
__global__ __launch_bounds__(256) void k_hist(const int* __restrict__ sel,
                                              int* __restrict__ counts) {
    int i = blockIdx.x * 256 + threadIdx.x;
    if (i < T_ * K_) atomicAdd(&counts[sel[i]], 1);
}

__global__ __launch_bounds__(512) void k_scan(const int* __restrict__ counts,
                                              int* __restrict__ offsets,
                                              int* __restrict__ cursor) {
    __shared__ int s[512];
    const int t = threadIdx.x;
    const int c = counts[t];
    s[t] = c;
    __syncthreads();
    for (int d = 1; d < 512; d <<= 1) {
        int v = (t >= d) ? s[t - d] : 0;
        __syncthreads();
        s[t] += v;
        __syncthreads();
    }
    offsets[t] = s[t] - c;
    cursor[t]  = s[t] - c;
    if (t == 511) offsets[512] = s[511];
}

__global__ __launch_bounds__(256) void k_scatter(const int* __restrict__ sel,
                                                 int* __restrict__ cursor,
                                                 int* __restrict__ bucket) {
    int i = blockIdx.x * 256 + threadIdx.x;
    if (i < T_ * K_) {
        int p = sel[i];
        int pos = atomicAdd(&cursor[p], 1);
        bucket[pos] = i;
    }
}

// ---------------------------------------------------------------------------
// K1: expert-grouped sel_mod. Block p reads its bucket, MFMA GEMM:
//     Y[pair][m] = dot(x[token], cm_w[p*64+m]) + cm_b[p*64+m]   (f32 out)
// ---------------------------------------------------------------------------
__global__ __launch_bounds__(256) void k_selmod(
    const float* __restrict__ x, const float* __restrict__ cm_w,
    const float* __restrict__ cm_b, const int* __restrict__ bucket,
    const int* __restrict__ offsets, float* __restrict__ Y)
{
    const int p   = blockIdx.x;
    const int tid = threadIdx.x;
    __shared__ int list[1024];
    __shared__ __align__(16) __bf16 Xl[64][136];
    __shared__ __align__(16) __bf16 Wl[64][136];

    const int off = offsets[p];
    const int n   = min(offsets[p + 1] - off, 1024);
    for (int i = tid; i < n; i += 256) list[i] = bucket[off + i];
    __syncthreads();
    if (n == 0) return;

    const int wave = tid >> 6, lane = tid & 63, quad = lane >> 4, l15 = lane & 15;
    const int srow = tid & 63;
    const int c0   = (tid >> 6) * 32;

    const float* wrow = cm_w + (long)(p * 64 + srow) * DM_;

    for (int base = 0; base < n; base += 64) {
        f32x4 acc[4] = {};
        int li = base + srow; if (li >= n) li = n - 1;
        const float* xrow = x + (long)(list[li] >> 3) * DM_;

        for (int kc = 0; kc < DM_; kc += 128) {
            const float4* xs = (const float4*)(xrow + kc + c0);
            const float4* ws = (const float4*)(wrow + kc + c0);
            #pragma unroll
            for (int u = 0; u < 8; ++u) {
                float4 xv = xs[u], wv = ws[u];
                bf16x4 xb, wb;
                xb[0]=(__bf16)xv.x; xb[1]=(__bf16)xv.y; xb[2]=(__bf16)xv.z; xb[3]=(__bf16)xv.w;
                wb[0]=(__bf16)wv.x; wb[1]=(__bf16)wv.y; wb[2]=(__bf16)wv.z; wb[3]=(__bf16)wv.w;
                *(bf16x4*)&Xl[srow][c0 + u * 4] = xb;
                *(bf16x4*)&Wl[srow][c0 + u * 4] = wb;
            }
            __syncthreads();
            #pragma unroll
            for (int ks = 0; ks < 4; ++ks) {
                const int ko = ks * 32 + quad * 8;
                bf16x8 bfr = *(const bf16x8*)&Wl[wave * 16 + l15][ko];
                #pragma unroll
                for (int i = 0; i < 4; ++i) {
                    bf16x8 afr = *(const bf16x8*)&Xl[i * 16 + l15][ko];
                    acc[i] = __builtin_amdgcn_mfma_f32_16x16x32_bf16(afr, bfr, acc[i], 0, 0, 0);
                }
            }
            __syncthreads();
        }
        const int   mcol = wave * 16 + l15;
        const float bias = cm_b[p * 64 + mcol];
        #pragma unroll
        for (int i = 0; i < 4; ++i) {
            #pragma unroll
            for (int r = 0; r < 4; ++r) {
                int prow = base + i * 16 + quad * 4 + r;
                if (prow < n)
                    Y[(long)list[prow] * MD_ + mcol] = acc[i][r] + bias;
            }
        }
    }
}

// ---------------------------------------------------------------------------
// K2a: build dense combine matrix Wd[4096][576] bf16:
//      cols 0..511: softmax weights scattered at sel (dup-safe, serial per token)
//      cols 512..575: wmod[m] = sum_k w_k * Y[t,k,m]
//      4 tokens per block, rows built in LDS then streamed out.
// ---------------------------------------------------------------------------
__global__ __launch_bounds__(256) void k_wdense(
    const float* __restrict__ Y, const int* __restrict__ sel,
    const float* __restrict__ pw, __bf16* __restrict__ Wd)
{
    const int tid = threadIdx.x;
    const int tt = tid >> 6, m = tid & 63;
    const int t = blockIdx.x * 4 + tt;
    __shared__ float w_s[4][8];
    __shared__ int   sidx[4][8];
    __shared__ __align__(16) __bf16 row[4][KC_];

    if (m < 8) {
        w_s[tt][m]  = pw[t * 8 + m];
        sidx[tt][m] = sel[t * 8 + m];
    }
    __syncthreads();
    if (m == 0) {
        float mx = w_s[tt][0];
        #pragma unroll
        for (int k = 1; k < 8; ++k) mx = fmaxf(mx, w_s[tt][k]);
        float sum = 0.f;
        #pragma unroll
        for (int k = 0; k < 8; ++k) { float e = expf(w_s[tt][k] - mx); w_s[tt][k] = e; sum += e; }
        float inv = 1.f / sum;
        #pragma unroll
        for (int k = 0; k < 8; ++k) w_s[tt][k] *= inv;
    }
    __syncthreads();
    *(uint4*)&row[tt][m * 8] = make_uint4(0, 0, 0, 0);   // zero cols 0..511
    float a = 0.f;
    #pragma unroll
    for (int k = 0; k < 8; ++k) a += w_s[tt][k] * Y[((long)t * 8 + k) * MD_ + m];
    row[tt][512 + m] = (__bf16)a;
    __syncthreads();
    if (m == 0) {
        #pragma unroll
        for (int k = 0; k < 8; ++k) {
            int c = sidx[tt][k];
            row[tt][c] = (__bf16)((float)row[tt][c] + w_s[tt][k]);  // serial: dup-safe
        }
    }
    __syncthreads();
    const uint4* src = (const uint4*)&row[0][0];
    uint4* dst = (uint4*)(Wd + (long)blockIdx.x * 4 * KC_);
    for (int e = tid; e < 4 * KC_ * 2 / 16; e += 256) dst[e] = src[e];
}

// ---------------------------------------------------------------------------
// K2b: P[4096][576] bf16: P[f][c] = bp[c][f] (c<512) / adj[c-512][f].
//      LDS-tiled 64x64 transpose+convert. grid (9, 64).
// ---------------------------------------------------------------------------
__global__ __launch_bounds__(256) void k_buildP(
    const float* __restrict__ bp, const float* __restrict__ adj,
    __bf16* __restrict__ P)
{
    __shared__ __bf16 tile[64][72];
    const int tid = threadIdx.x;
    const int bx = blockIdx.x, f0 = blockIdx.y * 64;
    const float* src = (bx < 8) ? (bp + (long)bx * 64 * DFF_) : adj;
    for (int e = tid; e < 4096; e += 256) {
        int f = e & 63, c = e >> 6;
        tile[c][f] = (__bf16)src[(long)c * DFF_ + f0 + f];
    }
    __syncthreads();
    const int c0 = bx * 64;
    for (int e = tid; e < 4096; e += 256) {
        int c = e & 63, f = e >> 6;
        P[(long)(f0 + f) * KC_ + c0 + c] = tile[c][f];
    }
}

// ---------------------------------------------------------------------------
// K0: f32 -> bf16 convert for w2. n16 = n/16.
// ---------------------------------------------------------------------------
__global__ __launch_bounds__(256) void k_cvt(const float* __restrict__ src,
                                             __bf16* __restrict__ dst, int n16) {
    int i = blockIdx.x * 256 + threadIdx.x;
    if (i >= n16) return;
    const float4* s = (const float4*)src + (long)i * 4;
    float4 a = s[0], b = s[1], c = s[2], d = s[3];
    bf16x8 o0, o1;
    o0[0]=(__bf16)a.x; o0[1]=(__bf16)a.y; o0[2]=(__bf16)a.z; o0[3]=(__bf16)a.w;
    o0[4]=(__bf16)b.x; o0[5]=(__bf16)b.y; o0[6]=(__bf16)b.z; o0[7]=(__bf16)b.w;
    o1[0]=(__bf16)c.x; o1[1]=(__bf16)c.y; o1[2]=(__bf16)c.z; o1[3]=(__bf16)c.w;
    o1[4]=(__bf16)d.x; o1[5]=(__bf16)d.y; o1[6]=(__bf16)d.z; o1[7]=(__bf16)d.w;
    bf16x8* dp = (bf16x8*)dst + (long)i * 2;
    dp[0] = o0; dp[1] = o1;
}

// ---------------------------------------------------------------------------
// K2c: act[4096][4096] = gelu( Wd[4096][576] @ P[4096][576]^T )  bf16 out
//      m97 structure: 128x128 tile, BK=32, async global->LDS staging.
// ---------------------------------------------------------------------------
__global__ __launch_bounds__(256) void k_actgemm(
    const __bf16* __restrict__ A, const __bf16* __restrict__ Bw,
    __bf16* __restrict__ act)
{
    __shared__ __align__(16) __bf16 sA[128 * 32];
    __shared__ __align__(16) __bf16 sB[128 * 32];
    const int tid  = threadIdx.x;
    const int tm   = blockIdx.y * 128, tn = blockIdx.x * 128;
    const int wave = tid >> 6, lane = tid & 63, quad = lane >> 4, l15 = lane & 15;
    const int wm   = (wave >> 1) * 64, wn = (wave & 1) * 64;

    f32x4 acc[4][4] = {};

    const int e    = tid * 8;
    const int srow = e >> 5;
    const int scol = e & 31;
    const __bf16* agp0 = A  + ((long)(tm + srow)      * KC_ + scol);
    const __bf16* agp1 = A  + ((long)(tm + 64 + srow) * KC_ + scol);
    const __bf16* bgp0 = Bw + ((long)(tn + srow)      * KC_ + scol);
    const __bf16* bgp1 = Bw + ((long)(tn + 64 + srow) * KC_ + scol);
    void* sa0 = (void*)(sA + e);
    void* sa1 = (void*)(sA + 2048 + e);
    void* sb0 = (void*)(sB + e);
    void* sb1 = (void*)(sB + 2048 + e);

    for (int kk = 0; kk < KC_; kk += 32) {
        async_ld16(agp0 + kk, sa0);
        async_ld16(agp1 + kk, sa1);
        async_ld16(bgp0 + kk, sb0);
        async_ld16(bgp1 + kk, sb1);
        __syncthreads();
        bf16x8 af[4], bf[4];
        #pragma unroll
        for (int i = 0; i < 4; ++i)
            af[i] = *(const bf16x8*)(sA + (wm + i * 16 + l15) * 32 + quad * 8);
        #pragma unroll
        for (int j = 0; j < 4; ++j)
            bf[j] = *(const bf16x8*)(sB + (wn + j * 16 + l15) * 32 + quad * 8);
        #pragma unroll
        for (int i = 0; i < 4; ++i)
            #pragma unroll
            for (int j = 0; j < 4; ++j)
                acc[i][j] = __builtin_amdgcn_mfma_f32_16x16x32_bf16(af[i], bf[j], acc[i][j], 0, 0, 0);
        __syncthreads();
    }

    #pragma unroll
    for (int j = 0; j < 4; ++j) {
        const int col = tn + wn + j * 16 + l15;
        #pragma unroll
        for (int i = 0; i < 4; ++i) {
            const int row = tm + wm + i * 16 + quad * 4;
            #pragma unroll
            for (int r = 0; r < 4; ++r)
                act[(long)(row + r) * DFF_ + col] = (__bf16)gelu_exact(acc[i][j][r]);
        }
    }
}

// ---------------------------------------------------------------------------
// K3: out[4096][1024] = act[4096][4096](bf16) @ w2bf[1024][4096]^T + w2_b
// ---------------------------------------------------------------------------
__global__ __launch_bounds__(256) void k_outgemm(
    const __bf16* __restrict__ A, const __bf16* __restrict__ Bw,
    const float* __restrict__ bias, float* __restrict__ out)
{
    __shared__ __align__(16) __bf16 sA[128 * 32];
    __shared__ __align__(16) __bf16 sB[128 * 32];
    const int tid  = threadIdx.x;
    const int tm   = blockIdx.y * 128, tn = blockIdx.x * 128;
    const int wave = tid >> 6, lane = tid & 63, quad = lane >> 4, l15 = lane & 15;
    const int wm   = (wave >> 1) * 64, wn = (wave & 1) * 64;

    f32x4 acc[4][4] = {};

    const int e    = tid * 8;
    const int srow = e >> 5;
    const int scol = e & 31;
    const __bf16* agp0 = A  + ((long)(tm + srow)      * DFF_ + scol);
    const __bf16* agp1 = A  + ((long)(tm + 64 + srow) * DFF_ + scol);
    const __bf16* bgp0 = Bw + ((long)(tn + srow)      * DFF_ + scol);
    const __bf16* bgp1 = Bw + ((long)(tn + 64 + srow) * DFF_ + scol);
    void* sa0 = (void*)(sA + e);
    void* sa1 = (void*)(sA + 2048 + e);
    void* sb0 = (void*)(sB + e);
    void* sb1 = (void*)(sB + 2048 + e);

    for (int kk = 0; kk < DFF_; kk += 32) {
        async_ld16(agp0 + kk, sa0);
        async_ld16(agp1 + kk, sa1);
        async_ld16(bgp0 + kk, sb0);
        async_ld16(bgp1 + kk, sb1);
        __syncthreads();
        bf16x8 af[4], bf[4];
        #pragma unroll
        for (int i = 0; i < 4; ++i)
            af[i] = *(const bf16x8*)(sA + (wm + i * 16 + l15) * 32 + quad * 8);
        #pragma unroll
        for (int j = 0; j < 4; ++j)
            bf[j] = *(const bf16x8*)(sB + (wn + j * 16 + l15) * 32 + quad * 8);
        #pragma unroll
        for (int i = 0; i < 4; ++i)
            #pragma unroll
            for (int j = 0; j < 4; ++j)
                acc[i][j] = __builtin_amdgcn_mfma_f32_16x16x32_bf16(af[i], bf[j], acc[i][j], 0, 0, 0);
        __syncthreads();
    }

    #pragma unroll
    for (int j = 0; j < 4; ++j) {
        const int col = tn + wn + j * 16 + l15;
        const float bj = bias[col];
        #pragma unroll
        for (int i = 0; i < 4; ++i) {
            const int row = tm + wm + i * 16 + quad * 4;
            #pragma unroll
            for (int r = 0; r < 4; ++r)
                out[(long)(row + r) * 1024 + col] = acc[i][j][r] + bj;
        }
    }
}

// ---------------------------------------------------------------------------
extern "C" void kernel_launch(void* const* d_in, const int* in_sizes, int n_in,
                              void* d_out, int out_size, void* d_ws, size_t ws_size,
                              hipStream_t stream) {
    const float* x    = (const float*)d_in[0];
    const int*   sel  = (const int*)  d_in[1];
    const float* pw   = (const float*)d_in[2];
    const float* bp   = (const float*)d_in[3];
    const float* cm_w = (const float*)d_in[4];
    const float* cm_b = (const float*)d_in[5];
    const float* adj  = (const float*)d_in[6];
    const float* w2   = (const float*)d_in[7];
    const float* w2b  = (const float*)d_in[8];
    float* out = (float*)d_out;

    // ws (<=46MB): act 32M | P 4.72M | w2bf 8M | bins ~0.14M
    char* ws = (char*)d_ws;
    __bf16* act  = (__bf16*)ws;
    __bf16* P    = (__bf16*)(ws + (size_t)32 * 1024 * 1024);
    __bf16* w2bf = (__bf16*)(ws + (size_t)37 * 1024 * 1024);
    char*  bins  = ws + (size_t)45 * 1024 * 1024;
    int* bucket  = (int*)bins;                 // 131072 B
    int* counts  = (int*)(bins + 131072);      // 2048 B
    int* cursor  = (int*)(bins + 133120);      // 2048 B
    int* offsets = (int*)(bins + 135168);      // 2052 B

    // d_out as staging (fully consumed before k_outgemm): Y f32 8M | Wd 4.72M
    float*  Y  = (float*)d_out;
    __bf16* Wd = (__bf16*)((char*)d_out + (size_t)8 * 1024 * 1024);

    hipMemsetAsync(counts, 0, 4096, stream);   // counts + cursor
    k_hist   <<<128, 256, 0, stream>>>(sel, counts);
    k_scan   <<<1,   512, 0, stream>>>(counts, offsets, cursor);
    k_scatter<<<128, 256, 0, stream>>>(sel, cursor, bucket);
    k_selmod <<<POOL_, 256, 0, stream>>>(x, cm_w, cm_b, bucket, offsets, Y);
    k_wdense <<<T_ / 4, 256, 0, stream>>>(Y, sel, pw, Wd);
    k_buildP <<<dim3(9, 64), 256, 0, stream>>>(bp, adj, P);
    k_cvt    <<<1024, 256, 0, stream>>>(w2, w2bf, DM_ * DFF_ / 16);
    k_actgemm<<<dim3(DFF_ / 128, T_ / 128), 256, 0, stream>>>(Wd, P, act);
    k_outgemm<<<dim3(DM_ / 128, T_ / 128), 256, 0, stream>>>(act, w2bf, w2b, out);
}